// Round 1
// baseline (2532.135 us; speedup 1.0000x reference)
//
#include <hip/hip_runtime.h>
#include <cstddef>

// Problem constants
constexpr int Bz = 8, CIN = 256, Hh = 96, Ww = 96;
constexpr int EMB1 = 256, EMB2 = 128, NCLS = 80;
constexpr int HP = 98; // padded spatial
constexpr size_t PIX = (size_t)Hh * Ww;                 // 9216
constexpr size_t XP_ELEMS = (size_t)Bz * HP * HP * CIN; // 19,668,992 (fp32 NHWC padded)
constexpr size_t HP_ELEMS = (size_t)Bz * HP * HP * EMB1;

// Output layout (flat concat, fp32)
constexpr size_t O0 = 0;                       // cls_score      (B,80,96,96)
constexpr size_t O1 = (size_t)Bz * NCLS * PIX; // cls_score_neg
constexpr size_t O2 = 2 * O1;                  // distances      (B,80,1,96,96)
constexpr size_t O3 = 3 * O1;                  // distances_neg  (B,80,3,96,96)
constexpr size_t O4 = 6 * O1;                  // probs_ori

// ---------------------------------------------------------------------------
// Prep: x (NCHW fp32) -> padded NHWC fp32, zero border
__global__ __launch_bounds__(256) void pad_x_kernel(const float* __restrict__ x,
                                                    float* __restrict__ xp) {
  const int p = blockIdx.x;       // 0..98*98-1
  const int b = blockIdx.y;
  const int ic = threadIdx.x;     // 0..255
  const int y = p / HP, xx = p % HP;
  float v = 0.f;
  if (y >= 1 && y <= Hh && xx >= 1 && xx <= Ww)
    v = x[(((size_t)b * CIN + ic) * Hh + (y - 1)) * Ww + (xx - 1)];
  xp[((size_t)b * (HP * HP) + p) * CIN + ic] = v;
}

// Prep: weights -> [tap][oc][ic]; BN fold
__global__ __launch_bounds__(256) void prep_w_kernel(
    const float* __restrict__ w1, const float* __restrict__ w2,
    const float* __restrict__ c1b, const float* __restrict__ g,
    const float* __restrict__ be, const float* __restrict__ mu,
    const float* __restrict__ var, float* __restrict__ wt1,
    float* __restrict__ wt2, float* __restrict__ bns, float* __restrict__ bno) {
  const int idx = blockIdx.x * 256 + threadIdx.x;
  if (idx < 9 * 256 * 256) {  // wt1[tap][oc][ic]
    const int ic = idx & 255, oc = (idx >> 8) & 255, tap = idx >> 16;
    wt1[idx] = w1[((size_t)(oc * 256 + ic)) * 9 + tap];
  }
  if (idx < 9 * 128 * 256) {  // wt2[tap][oc][ic]
    const int ic = idx & 255, oc = (idx >> 8) & 127, tap = idx >> 15;
    wt2[idx] = w2[((size_t)(oc * 256 + ic)) * 9 + tap];
  }
  if (idx < 256) {
    const float s = g[idx] * rsqrtf(var[idx] + 1e-5f);
    bns[idx] = s;
    bno[idx] = (c1b[idx] - mu[idx]) * s + be[idx];
  }
}

// reps = l2norm(rep_w[:,0] + rep_b) per class (80 x 128)
__global__ __launch_bounds__(128) void rep_norm_kernel(const float* __restrict__ rw,
                                                       const float* __restrict__ rb,
                                                       float* __restrict__ r) {
  __shared__ float red[2];
  const int c = blockIdx.x, t = threadIdx.x;
  const float v = rw[c * 128 + t] + rb[c * 128 + t];
  float s = v * v;
  for (int msk = 1; msk < 64; msk <<= 1) s += __shfl_xor(s, msk, 64);
  if ((t & 63) == 0) red[t >> 6] = s;
  __syncthreads();
  const float ss = red[0] + red[1];
  const float rn = 1.f / fmaxf(sqrtf(ss), 1e-12f);
  r[c * 128 + t] = v * rn;
}

// reps_neg: per (class, neg) 3-layer MLP on r, then l2norm
__global__ __launch_bounds__(128) void mlp_neg_kernel(const float* __restrict__ r,
                                                      const float* __restrict__ W,
                                                      const float* __restrict__ bb,
                                                      float* __restrict__ outr) {
  __shared__ float h0[128], h1[128];
  __shared__ float red[2];
  const int c = blockIdx.x, ng = blockIdx.y, t = threadIdx.x;
  h0[t] = r[c * 128 + t];
  __syncthreads();
  float s = 0.f;
  for (int lay = 0; lay < 3; ++lay) {
    const float* hin = (lay & 1) ? h1 : h0;
    float* hout = (lay & 1) ? h0 : h1;
    const float* wr = W + (((size_t)ng * 3 + lay) * 128 + t) * 128;
    s = bb[(ng * 3 + lay) * 128 + t];
    for (int e = 0; e < 128; ++e) s += wr[e] * hin[e];
    if (lay < 2) hout[t] = fmaxf(s, 0.f);
    __syncthreads();
  }
  float q = s * s;
  for (int msk = 1; msk < 64; msk <<= 1) q += __shfl_xor(q, msk, 64);
  if ((t & 63) == 0) red[t >> 6] = q;
  __syncthreads();
  const float ss = red[0] + red[1];
  const float rn = 1.f / fmaxf(sqrtf(ss), 1e-12f);
  outr[((size_t)c * 3 + ng) * 128 + t] = s * rn;
}

// ---------------------------------------------------------------------------
// Implicit-GEMM 3x3 conv, NHWC fp32. Tile: 64 px (4x16) x 64 oc, BK=16, 9 taps.
// BN=true: out = acc*e0[oc]+e1[oc] -> padded NHWC (B,98,98,EMB1) at (y+1,x+1)
// BN=false: out = acc+e0[oc]       -> NHWC (B,96,96,EMB2)
template <int OC, bool BN>
__global__ __launch_bounds__(256) void conv3x3_kernel(
    const float* __restrict__ in, const float* __restrict__ wt,
    const float* __restrict__ e0, const float* __restrict__ e1,
    float* __restrict__ out) {
  __shared__ float As[16][68];
  __shared__ float Bs[16][68];
  const int pt = blockIdx.x;          // 0..143
  const int oc0 = blockIdx.y * 64;
  const int b = blockIdx.z;
  const int ty = (pt / 6) * 4;
  const int tx = (pt % 6) * 16;
  const int t = threadIdx.x;
  const int m = t & 63;               // staging lane: pixel (A) / oc (B)
  const int part = t >> 6;            // 0..3 -> ic quarter
  const int sy = ty + (m >> 4);
  const int sx = tx + (m & 15);
  const int cpx = (t & 15) * 4;       // compute: 4 consecutive px
  const int coc = (t >> 4) * 4;       // compute: 4 consecutive oc

  float acc[4][4];
#pragma unroll
  for (int i = 0; i < 4; ++i)
#pragma unroll
    for (int j = 0; j < 4; ++j) acc[i][j] = 0.f;

  for (int tap = 0; tap < 9; ++tap) {
    const int ky = tap / 3, kx = tap % 3;
    const float* inp =
        in + (((size_t)b * HP + (sy + ky)) * HP + (sx + kx)) * 256 + part * 4;
    const float* wtp = wt + ((size_t)tap * OC + (oc0 + m)) * 256 + part * 4;
    for (int icc = 0; icc < 256; icc += 16) {
      const float4 av = *(const float4*)(inp + icc);
      const float4 bv = *(const float4*)(wtp + icc);
      __syncthreads();
      const int r0 = part * 4;
      As[r0 + 0][m] = av.x; As[r0 + 1][m] = av.y;
      As[r0 + 2][m] = av.z; As[r0 + 3][m] = av.w;
      Bs[r0 + 0][m] = bv.x; Bs[r0 + 1][m] = bv.y;
      Bs[r0 + 2][m] = bv.z; Bs[r0 + 3][m] = bv.w;
      __syncthreads();
#pragma unroll
      for (int k = 0; k < 16; ++k) {
        const float a0 = As[k][cpx + 0], a1 = As[k][cpx + 1];
        const float a2 = As[k][cpx + 2], a3 = As[k][cpx + 3];
        const float b0 = Bs[k][coc + 0], b1 = Bs[k][coc + 1];
        const float b2 = Bs[k][coc + 2], b3 = Bs[k][coc + 3];
        acc[0][0] += a0 * b0; acc[0][1] += a0 * b1;
        acc[0][2] += a0 * b2; acc[0][3] += a0 * b3;
        acc[1][0] += a1 * b0; acc[1][1] += a1 * b1;
        acc[1][2] += a1 * b2; acc[1][3] += a1 * b3;
        acc[2][0] += a2 * b0; acc[2][1] += a2 * b1;
        acc[2][2] += a2 * b2; acc[2][3] += a2 * b3;
        acc[3][0] += a3 * b0; acc[3][1] += a3 * b1;
        acc[3][2] += a3 * b2; acc[3][3] += a3 * b3;
      }
    }
  }
#pragma unroll
  for (int i = 0; i < 4; ++i) {
    const int p = cpx + i;
    const int oy = ty + (p >> 4), ox = tx + (p & 15);
#pragma unroll
    for (int j = 0; j < 4; ++j) {
      const int oc = oc0 + coc + j;
      float v = acc[i][j];
      if (BN) {
        v = v * e0[oc] + e1[oc];
        out[(((size_t)b * HP + (oy + 1)) * HP + (ox + 1)) * EMB1 + oc] = v;
      } else {
        v += e0[oc];
        out[(((size_t)b * Hh + oy) * Ww + ox) * EMB2 + oc] = v;
      }
    }
  }
}

// In-place l2norm over channel dim (128) of NHWC emb. 32 lanes per pixel.
__global__ __launch_bounds__(256) void l2norm_emb_kernel(float* __restrict__ emb) {
  const int t = threadIdx.x;
  const size_t px = (size_t)blockIdx.x * 8 + (t >> 5);
  const int lane = t & 31;
  float4 v = *(const float4*)(emb + px * 128 + lane * 4);
  float s = v.x * v.x + v.y * v.y + v.z * v.z + v.w * v.w;
  for (int msk = 1; msk < 32; msk <<= 1) s += __shfl_xor(s, msk, 64);
  const float rn = 1.f / fmaxf(sqrtf(s), 1e-12f);
  v.x *= rn; v.y *= rn; v.z *= rn; v.w *= rn;
  *(float4*)(emb + px * 128 + lane * 4) = v;
}

// ---------------------------------------------------------------------------
// Score kernel: per block 64 px x 8 classes (x 4 reps each: pos + 3 neg)
__global__ __launch_bounds__(256) void score_kernel(
    const float* __restrict__ emb, const float* __restrict__ rp,
    const float* __restrict__ rneg, float* __restrict__ out) {
  __shared__ float E[64][132];
  __shared__ float R[8 * 4 * 128];
  const int pt = blockIdx.x;
  const int cc = blockIdx.y * 8;
  const int b = blockIdx.z;
  const int ty = (pt / 6) * 4, tx = (pt % 6) * 16;
  const int t = threadIdx.x;
  {
    const int m = t & 63, part = t >> 6;
    const float* ep =
        emb + (((size_t)b * Hh + (ty + (m >> 4))) * Ww + (tx + (m & 15))) * 128;
#pragma unroll
    for (int i = 0; i < 8; ++i) {
      const float4 v = *(const float4*)(ep + (part * 8 + i) * 4);
      *(float4*)(&E[m][(part * 8 + i) * 4]) = v;
    }
  }
  for (int i = t; i < 8 * 4 * 32; i += 256) {
    const int vecid = i >> 5;
    const int k4 = i & 31;
    const int cls = vecid >> 2, vec = vecid & 3;
    const float* src = (vec == 0)
                           ? (rp + (size_t)(cc + cls) * 128)
                           : (rneg + ((size_t)(cc + cls) * 3 + (vec - 1)) * 128);
    *(float4*)(&R[vecid * 128 + k4 * 4]) = *(const float4*)(src + k4 * 4);
  }
  __syncthreads();
  const int px = t & 63;
  const int cb = t >> 6;
  const int oy = ty + (px >> 4), ox = tx + (px & 15);
  const size_t pix = (size_t)oy * Ww + ox;
#pragma unroll
  for (int pass = 0; pass < 2; ++pass) {
    const int c = cb + pass * 4;
    const float* Ep = &E[px][0];
    const float* R0 = &R[(c * 4 + 0) * 128];
    const float* R1 = &R[(c * 4 + 1) * 128];
    const float* R2 = &R[(c * 4 + 2) * 128];
    const float* R3 = &R[(c * 4 + 3) * 128];
    float dp = 0.f, d0 = 0.f, d1 = 0.f, d2 = 0.f;
#pragma unroll 8
    for (int k4 = 0; k4 < 32; ++k4) {
      const float4 e = *(const float4*)(Ep + k4 * 4);
      const float4 w0 = *(const float4*)(R0 + k4 * 4);
      const float4 w1 = *(const float4*)(R1 + k4 * 4);
      const float4 w2 = *(const float4*)(R2 + k4 * 4);
      const float4 w3 = *(const float4*)(R3 + k4 * 4);
      dp += e.x * w0.x + e.y * w0.y + e.z * w0.z + e.w * w0.w;
      d0 += e.x * w1.x + e.y * w1.y + e.z * w1.z + e.w * w1.w;
      d1 += e.x * w2.x + e.y * w2.y + e.z * w2.z + e.w * w2.w;
      d2 += e.x * w3.x + e.y * w3.y + e.z * w3.z + e.w * w3.w;
    }
    const float dist = sqrtf(fmaxf(2.f - 2.f * dp, 0.f));
    const float dn0 = sqrtf(fmaxf(2.f - 2.f * d0, 0.f));
    const float dn1 = sqrtf(fmaxf(2.f - 2.f * d1, 0.f));
    const float dn2 = sqrtf(fmaxf(2.f - 2.f * d2, 0.f));
    const float pn = fmaxf(fmaxf(expf(-2.f * dn0 * dn0), expf(-2.f * dn1 * dn1)),
                           expf(-2.f * dn2 * dn2));
    const float pori = expf(-2.f * dist * dist);
    const float minn = fminf(dn0, fminf(dn1, dn2));
    const float shifted = dist + 0.3f * fmaxf(2.0f - minn, 0.f);
    const float p = expf(-2.f * shifted * shifted);
    const float clsv = logf(fmaxf(p, 1e-5f) / fmaxf(1.f - p, 1e-5f));
    const int gc = cc + c;
    const size_t bc = ((size_t)b * NCLS + gc) * PIX + pix;
    out[O0 + bc] = clsv;
    out[O1 + bc] = pn;
    out[O2 + bc] = dist;
    out[O4 + bc] = pori;
    const size_t b3 = (((size_t)b * NCLS + gc) * 3) * PIX + pix;
    out[O3 + b3] = dn0;
    out[O3 + b3 + PIX] = dn1;
    out[O3 + b3 + 2 * PIX] = dn2;
  }
}

// ---------------------------------------------------------------------------
extern "C" void kernel_launch(void* const* d_in, const int* in_sizes, int n_in,
                              void* d_out, int out_size, void* d_ws,
                              size_t ws_size, hipStream_t stream) {
  const float* x = (const float*)d_in[0];
  const float* w1 = (const float*)d_in[1];
  const float* c1b = (const float*)d_in[2];
  const float* g = (const float*)d_in[3];
  const float* be = (const float*)d_in[4];
  const float* mu = (const float*)d_in[5];
  const float* var = (const float*)d_in[6];
  const float* w2 = (const float*)d_in[7];
  const float* c2b = (const float*)d_in[8];
  const float* rw = (const float*)d_in[9];
  const float* rb = (const float*)d_in[10];
  const float* nw = (const float*)d_in[11];
  const float* nb = (const float*)d_in[12];
  float* out = (float*)d_out;

  float* ws = (float*)d_ws;
  float* xp = ws;                       // 19,668,992 fp32 (padded NHWC input)
  float* hp = xp + XP_ELEMS;            // 19,668,992 fp32 (padded NHWC hidden)
  float* wt1 = hp + HP_ELEMS;           // 589,824
  float* wt2 = wt1 + 589824;            // 294,912
  float* bns = wt2 + 294912;            // 256
  float* bno = bns + 256;               // 256
  float* rpv = bno + 256;               // 10,240
  float* rneg = rpv + 10240;            // 30,720
  float* emb = xp;                      // alias: xp dead after conv1

  hipMemsetAsync(hp, 0, HP_ELEMS * sizeof(float), stream);
  pad_x_kernel<<<dim3(HP * HP, Bz), 256, 0, stream>>>(x, xp);
  prep_w_kernel<<<2304, 256, 0, stream>>>(w1, w2, c1b, g, be, mu, var, wt1, wt2,
                                          bns, bno);
  rep_norm_kernel<<<NCLS, 128, 0, stream>>>(rw, rb, rpv);
  mlp_neg_kernel<<<dim3(NCLS, 3), 128, 0, stream>>>(rpv, nw, nb, rneg);
  conv3x3_kernel<256, true><<<dim3(144, 4, Bz), 256, 0, stream>>>(xp, wt1, bns,
                                                                  bno, hp);
  conv3x3_kernel<128, false><<<dim3(144, 2, Bz), 256, 0, stream>>>(hp, wt2, c2b,
                                                                   nullptr, emb);
  l2norm_emb_kernel<<<(Bz * PIX) / 8, 256, 0, stream>>>(emb);
  score_kernel<<<dim3(144, 10, Bz), 256, 0, stream>>>(emb, rpv, rneg, out);
}

// Round 2
// 692.546 us; speedup vs baseline: 3.6563x; 3.6563x over previous
//
#include <hip/hip_runtime.h>
#include <cstddef>
#include <cstdint>

// Problem constants
constexpr int Bz = 8, CIN = 256, Hh = 96, Ww = 96;
constexpr int EMB1 = 256, EMB2 = 128, NCLS = 80;
constexpr int HP = 98; // padded spatial
constexpr size_t PIX = (size_t)Hh * Ww;                 // 9216
constexpr size_t XP_ELEMS = (size_t)Bz * HP * HP * CIN; // 19,668,992 bf16 elems

// Output layout (flat concat, fp32)
constexpr size_t O0 = 0;                       // cls_score      (B,80,96,96)
constexpr size_t O1 = (size_t)Bz * NCLS * PIX; // cls_score_neg
constexpr size_t O2 = 2 * O1;                  // distances
constexpr size_t O3 = 3 * O1;                  // distances_neg  (B,80,3,96,96)
constexpr size_t O4 = 6 * O1;                  // probs_ori

typedef short bf16x8 __attribute__((ext_vector_type(8)));
typedef float f32x4 __attribute__((ext_vector_type(4)));

__device__ inline unsigned short f2bf(float f) {
  union { float f; unsigned int u; } v; v.f = f;
  unsigned int r = v.u + 0x7fffu + ((v.u >> 16) & 1u);
  return (unsigned short)(r >> 16);
}

// async global->LDS, 16B per lane; LDS dest = wave-uniform base + lane*16
#define GLD16(gp, lp)                                              \
  __builtin_amdgcn_global_load_lds(                                \
      (__attribute__((address_space(1))) void*)((void*)(gp)),      \
      (__attribute__((address_space(3))) void*)(lp), 16, 0, 0)

// ---------------------------------------------------------------------------
// Prep: x (NCHW fp32) -> padded NHWC bf16, zero border
__global__ __launch_bounds__(256) void pad_x_kernel(const float* __restrict__ x,
                                                    unsigned short* __restrict__ xp) {
  const int p = blockIdx.x;       // 0..98*98-1
  const int b = blockIdx.y;
  const int ic = threadIdx.x;     // 0..255
  const int y = p / HP, xx = p % HP;
  float v = 0.f;
  if (y >= 1 && y <= Hh && xx >= 1 && xx <= Ww)
    v = x[(((size_t)b * CIN + ic) * Hh + (y - 1)) * Ww + (xx - 1)];
  xp[((size_t)b * (HP * HP) + p) * CIN + ic] = f2bf(v);
}

// Prep: weights -> bf16 [tap][oc][ic]; BN fold (fp32 scale/offset)
__global__ __launch_bounds__(256) void prep_w_kernel(
    const float* __restrict__ w1, const float* __restrict__ w2,
    const float* __restrict__ c1b, const float* __restrict__ g,
    const float* __restrict__ be, const float* __restrict__ mu,
    const float* __restrict__ var, unsigned short* __restrict__ wt1,
    unsigned short* __restrict__ wt2, float* __restrict__ bns,
    float* __restrict__ bno) {
  const int idx = blockIdx.x * 256 + threadIdx.x;
  if (idx < 9 * 256 * 256) {  // wt1[tap][oc][ic]
    const int ic = idx & 255, oc = (idx >> 8) & 255, tap = idx >> 16;
    wt1[idx] = f2bf(w1[((size_t)(oc * 256 + ic)) * 9 + tap]);
  }
  if (idx < 9 * 128 * 256) {  // wt2[tap][oc][ic]
    const int ic = idx & 255, oc = (idx >> 8) & 127, tap = idx >> 15;
    wt2[idx] = f2bf(w2[((size_t)(oc * 256 + ic)) * 9 + tap]);
  }
  if (idx < 256) {
    const float s = g[idx] * rsqrtf(var[idx] + 1e-5f);
    bns[idx] = s;
    bno[idx] = (c1b[idx] - mu[idx]) * s + be[idx];
  }
}

// reps = l2norm(rep_w[:,0] + rep_b) per class (80 x 128)
__global__ __launch_bounds__(128) void rep_norm_kernel(const float* __restrict__ rw,
                                                       const float* __restrict__ rb,
                                                       float* __restrict__ r) {
  __shared__ float red[2];
  const int c = blockIdx.x, t = threadIdx.x;
  const float v = rw[c * 128 + t] + rb[c * 128 + t];
  float s = v * v;
  for (int msk = 1; msk < 64; msk <<= 1) s += __shfl_xor(s, msk, 64);
  if ((t & 63) == 0) red[t >> 6] = s;
  __syncthreads();
  const float ss = red[0] + red[1];
  const float rn = 1.f / fmaxf(sqrtf(ss), 1e-12f);
  r[c * 128 + t] = v * rn;
}

// reps_neg: per (class, neg) 3-layer MLP on r, then l2norm
__global__ __launch_bounds__(128) void mlp_neg_kernel(const float* __restrict__ r,
                                                      const float* __restrict__ W,
                                                      const float* __restrict__ bb,
                                                      float* __restrict__ outr) {
  __shared__ float h0[128], h1[128];
  __shared__ float red[2];
  const int c = blockIdx.x, ng = blockIdx.y, t = threadIdx.x;
  h0[t] = r[c * 128 + t];
  __syncthreads();
  float s = 0.f;
  for (int lay = 0; lay < 3; ++lay) {
    const float* hin = (lay & 1) ? h1 : h0;
    float* hout = (lay & 1) ? h0 : h1;
    const float* wr = W + (((size_t)ng * 3 + lay) * 128 + t) * 128;
    s = bb[(ng * 3 + lay) * 128 + t];
    for (int e = 0; e < 128; ++e) s += wr[e] * hin[e];
    if (lay < 2) hout[t] = fmaxf(s, 0.f);
    __syncthreads();
  }
  float q = s * s;
  for (int msk = 1; msk < 64; msk <<= 1) q += __shfl_xor(q, msk, 64);
  if ((t & 63) == 0) red[t >> 6] = q;
  __syncthreads();
  const float ss = red[0] + red[1];
  const float rn = 1.f / fmaxf(sqrtf(ss), 1e-12f);
  outr[((size_t)c * 3 + ng) * 128 + t] = s * rn;
}

// ---------------------------------------------------------------------------
// bf16 MFMA implicit-GEMM 3x3 conv, NHWC (padded input HPxHP, IC=256).
// Block tile: 128 px (8 rows x 16 cols) x 128 oc. BK=32. 4 waves, each 64x64
// via 4x4 grid of mfma_f32_16x16x32_bf16. global_load_lds width-16 staging.
// BN=true: out bf16 padded NHWC (B,98,98,256) at (y+1,x+1), v=acc*e0+e1
// BN=false: out fp32 NHWC (B,96,96,128), v=acc+e0
template <int OC, bool BN>
__global__ __launch_bounds__(256) void conv3x3_mfma(
    const unsigned short* __restrict__ in, const unsigned short* __restrict__ wt,
    const float* __restrict__ e0, const float* __restrict__ e1,
    void* __restrict__ outp) {
  __shared__ unsigned short smA[128 * 32];  // [px][k] 64B rows
  __shared__ unsigned short smB[128 * 32];  // [oc][k]
  const int tile = blockIdx.x;              // 0..71
  const int oc0 = blockIdx.y * 128;
  const int b = blockIdx.z;
  const int ty = (tile / 6) * 8, tx = (tile % 6) * 16;
  const int t = threadIdx.x;
  const int lane = t & 63, w = t >> 6;
  const int wm = w & 1, wn = w >> 1;
  const int quad = lane >> 4, col = lane & 15;
  const int chl = (lane & 3) * 8;           // staging channel sub-offset

  int rowA[2], colA[2], ocB[2];
#pragma unroll
  for (int i = 0; i < 2; ++i) {
    const int px = (w * 2 + i) * 16 + (lane >> 2);
    rowA[i] = ty + (px >> 4);
    colA[i] = tx + (px & 15);
    ocB[i] = oc0 + (w * 2 + i) * 16 + (lane >> 2);
  }

  f32x4 acc[4][4];
#pragma unroll
  for (int mt = 0; mt < 4; ++mt)
#pragma unroll
    for (int nt = 0; nt < 4; ++nt) acc[mt][nt] = {0.f, 0.f, 0.f, 0.f};

  for (int tap = 0; tap < 9; ++tap) {
    const int ky = tap / 3, kx = tap % 3;
    const unsigned short* aB[2];
    const unsigned short* bB[2];
#pragma unroll
    for (int i = 0; i < 2; ++i) {
      aB[i] = in + (((size_t)b * HP + rowA[i] + ky) * HP + colA[i] + kx) * 256 + chl;
      bB[i] = wt + ((size_t)(tap * OC + ocB[i])) * 256 + chl;
    }
    for (int ch0 = 0; ch0 < 256; ch0 += 32) {
      __syncthreads();
      GLD16(aB[0] + ch0, (char*)smA + (w * 2 + 0) * 1024);
      GLD16(aB[1] + ch0, (char*)smA + (w * 2 + 1) * 1024);
      GLD16(bB[0] + ch0, (char*)smB + (w * 2 + 0) * 1024);
      GLD16(bB[1] + ch0, (char*)smB + (w * 2 + 1) * 1024);
      __syncthreads();
      bf16x8 af[4], bf[4];
#pragma unroll
      for (int mt = 0; mt < 4; ++mt)
        af[mt] = *(const bf16x8*)((const char*)smA +
                                  (wm * 64 + mt * 16 + col) * 64 + quad * 16);
#pragma unroll
      for (int nt = 0; nt < 4; ++nt)
        bf[nt] = *(const bf16x8*)((const char*)smB +
                                  (wn * 64 + nt * 16 + col) * 64 + quad * 16);
#pragma unroll
      for (int mt = 0; mt < 4; ++mt)
#pragma unroll
        for (int nt = 0; nt < 4; ++nt)
          acc[mt][nt] = __builtin_amdgcn_mfma_f32_16x16x32_bf16(
              af[mt], bf[nt], acc[mt][nt], 0, 0, 0);
    }
  }

  // epilogue
  float sc[4], of[4];
#pragma unroll
  for (int nt = 0; nt < 4; ++nt) {
    const int oc = oc0 + wn * 64 + nt * 16 + col;
    sc[nt] = e0[oc];
    of[nt] = BN ? e1[oc] : 0.f;
  }
  if (BN) {
    unsigned short* out16 = (unsigned short*)outp;
#pragma unroll
    for (int mt = 0; mt < 4; ++mt)
#pragma unroll
      for (int r = 0; r < 4; ++r) {
        const int px = wm * 64 + mt * 16 + quad * 4 + r;
        const int y = ty + (px >> 4), x = tx + (px & 15);
        unsigned short* rowp =
            out16 + (((size_t)b * HP + y + 1) * HP + x + 1) * 256 + oc0 + wn * 64 + col;
#pragma unroll
        for (int nt = 0; nt < 4; ++nt)
          rowp[nt * 16] = f2bf(acc[mt][nt][r] * sc[nt] + of[nt]);
      }
  } else {
    float* outf = (float*)outp;
#pragma unroll
    for (int mt = 0; mt < 4; ++mt)
#pragma unroll
      for (int r = 0; r < 4; ++r) {
        const int px = wm * 64 + mt * 16 + quad * 4 + r;
        const int y = ty + (px >> 4), x = tx + (px & 15);
        float* rowp =
            outf + (((size_t)b * Hh + y) * Ww + x) * EMB2 + oc0 + wn * 64 + col;
#pragma unroll
        for (int nt = 0; nt < 4; ++nt)
          rowp[nt * 16] = acc[mt][nt][r] + sc[nt];
      }
  }
}

// In-place l2norm over channel dim (128) of NHWC emb. 32 lanes per pixel.
__global__ __launch_bounds__(256) void l2norm_emb_kernel(float* __restrict__ emb) {
  const int t = threadIdx.x;
  const size_t px = (size_t)blockIdx.x * 8 + (t >> 5);
  const int lane = t & 31;
  float4 v = *(const float4*)(emb + px * 128 + lane * 4);
  float s = v.x * v.x + v.y * v.y + v.z * v.z + v.w * v.w;
  for (int msk = 1; msk < 32; msk <<= 1) s += __shfl_xor(s, msk, 64);
  const float rn = 1.f / fmaxf(sqrtf(s), 1e-12f);
  v.x *= rn; v.y *= rn; v.z *= rn; v.w *= rn;
  *(float4*)(emb + px * 128 + lane * 4) = v;
}

// ---------------------------------------------------------------------------
// Score kernel: per block 64 px x 8 classes (x 4 reps each: pos + 3 neg)
__global__ __launch_bounds__(256) void score_kernel(
    const float* __restrict__ emb, const float* __restrict__ rp,
    const float* __restrict__ rneg, float* __restrict__ out) {
  __shared__ float E[64][132];
  __shared__ float R[8 * 4 * 128];
  const int pt = blockIdx.x;
  const int cc = blockIdx.y * 8;
  const int b = blockIdx.z;
  const int ty = (pt / 6) * 4, tx = (pt % 6) * 16;
  const int t = threadIdx.x;
  {
    const int m = t & 63, part = t >> 6;
    const float* ep =
        emb + (((size_t)b * Hh + (ty + (m >> 4))) * Ww + (tx + (m & 15))) * 128;
#pragma unroll
    for (int i = 0; i < 8; ++i) {
      const float4 v = *(const float4*)(ep + (part * 8 + i) * 4);
      *(float4*)(&E[m][(part * 8 + i) * 4]) = v;
    }
  }
  for (int i = t; i < 8 * 4 * 32; i += 256) {
    const int vecid = i >> 5;
    const int k4 = i & 31;
    const int cls = vecid >> 2, vec = vecid & 3;
    const float* src = (vec == 0)
                           ? (rp + (size_t)(cc + cls) * 128)
                           : (rneg + ((size_t)(cc + cls) * 3 + (vec - 1)) * 128);
    *(float4*)(&R[vecid * 128 + k4 * 4]) = *(const float4*)(src + k4 * 4);
  }
  __syncthreads();
  const int px = t & 63;
  const int cb = t >> 6;
  const int oy = ty + (px >> 4), ox = tx + (px & 15);
  const size_t pix = (size_t)oy * Ww + ox;
#pragma unroll
  for (int pass = 0; pass < 2; ++pass) {
    const int c = cb + pass * 4;
    const float* Ep = &E[px][0];
    const float* R0 = &R[(c * 4 + 0) * 128];
    const float* R1 = &R[(c * 4 + 1) * 128];
    const float* R2 = &R[(c * 4 + 2) * 128];
    const float* R3 = &R[(c * 4 + 3) * 128];
    float dp = 0.f, d0 = 0.f, d1 = 0.f, d2 = 0.f;
#pragma unroll 8
    for (int k4 = 0; k4 < 32; ++k4) {
      const float4 e = *(const float4*)(Ep + k4 * 4);
      const float4 w0 = *(const float4*)(R0 + k4 * 4);
      const float4 w1 = *(const float4*)(R1 + k4 * 4);
      const float4 w2 = *(const float4*)(R2 + k4 * 4);
      const float4 w3 = *(const float4*)(R3 + k4 * 4);
      dp += e.x * w0.x + e.y * w0.y + e.z * w0.z + e.w * w0.w;
      d0 += e.x * w1.x + e.y * w1.y + e.z * w1.z + e.w * w1.w;
      d1 += e.x * w2.x + e.y * w2.y + e.z * w2.z + e.w * w2.w;
      d2 += e.x * w3.x + e.y * w3.y + e.z * w3.z + e.w * w3.w;
    }
    const float dist = sqrtf(fmaxf(2.f - 2.f * dp, 0.f));
    const float dn0 = sqrtf(fmaxf(2.f - 2.f * d0, 0.f));
    const float dn1 = sqrtf(fmaxf(2.f - 2.f * d1, 0.f));
    const float dn2 = sqrtf(fmaxf(2.f - 2.f * d2, 0.f));
    const float pn = fmaxf(fmaxf(expf(-2.f * dn0 * dn0), expf(-2.f * dn1 * dn1)),
                           expf(-2.f * dn2 * dn2));
    const float pori = expf(-2.f * dist * dist);
    const float minn = fminf(dn0, fminf(dn1, dn2));
    const float shifted = dist + 0.3f * fmaxf(2.0f - minn, 0.f);
    const float p = expf(-2.f * shifted * shifted);
    const float clsv = logf(fmaxf(p, 1e-5f) / fmaxf(1.f - p, 1e-5f));
    const int gc = cc + c;
    const size_t bc = ((size_t)b * NCLS + gc) * PIX + pix;
    out[O0 + bc] = clsv;
    out[O1 + bc] = pn;
    out[O2 + bc] = dist;
    out[O4 + bc] = pori;
    const size_t b3 = (((size_t)b * NCLS + gc) * 3) * PIX + pix;
    out[O3 + b3] = dn0;
    out[O3 + b3 + PIX] = dn1;
    out[O3 + b3 + 2 * PIX] = dn2;
  }
}

// ---------------------------------------------------------------------------
extern "C" void kernel_launch(void* const* d_in, const int* in_sizes, int n_in,
                              void* d_out, int out_size, void* d_ws,
                              size_t ws_size, hipStream_t stream) {
  const float* x = (const float*)d_in[0];
  const float* w1 = (const float*)d_in[1];
  const float* c1b = (const float*)d_in[2];
  const float* g = (const float*)d_in[3];
  const float* be = (const float*)d_in[4];
  const float* mu = (const float*)d_in[5];
  const float* var = (const float*)d_in[6];
  const float* w2 = (const float*)d_in[7];
  const float* c2b = (const float*)d_in[8];
  const float* rw = (const float*)d_in[9];
  const float* rb = (const float*)d_in[10];
  const float* nw = (const float*)d_in[11];
  const float* nb = (const float*)d_in[12];
  float* out = (float*)d_out;

  unsigned short* xp = (unsigned short*)d_ws;   // bf16 padded NHWC input
  unsigned short* hp = xp + XP_ELEMS;           // bf16 padded NHWC hidden
  unsigned short* wt1 = hp + XP_ELEMS;          // 589,824 bf16
  unsigned short* wt2 = wt1 + 589824;           // 294,912 bf16
  float* bns = (float*)(wt2 + 294912);
  float* bno = bns + 256;
  float* rpv = bno + 256;                       // 10,240 fp32
  float* rneg = rpv + 10240;                    // 30,720 fp32
  float* emb = (float*)xp;                      // alias: xp dead after conv1

  hipMemsetAsync(hp, 0, XP_ELEMS * sizeof(unsigned short), stream);
  pad_x_kernel<<<dim3(HP * HP, Bz), 256, 0, stream>>>(x, xp);
  prep_w_kernel<<<2304, 256, 0, stream>>>(w1, w2, c1b, g, be, mu, var, wt1, wt2,
                                          bns, bno);
  rep_norm_kernel<<<NCLS, 128, 0, stream>>>(rw, rb, rpv);
  mlp_neg_kernel<<<dim3(NCLS, 3), 128, 0, stream>>>(rpv, nw, nb, rneg);
  conv3x3_mfma<256, true><<<dim3(72, 2, Bz), 256, 0, stream>>>(xp, wt1, bns,
                                                               bno, hp);
  conv3x3_mfma<128, false><<<dim3(72, 1, Bz), 256, 0, stream>>>(hp, wt2, c2b,
                                                                nullptr, emb);
  l2norm_emb_kernel<<<(Bz * PIX) / 8, 256, 0, stream>>>(emb);
  score_kernel<<<dim3(144, 10, Bz), 256, 0, stream>>>(emb, rpv, rneg, out);
}

// Round 3
// 580.388 us; speedup vs baseline: 4.3628x; 1.1932x over previous
//
#include <hip/hip_runtime.h>
#include <cstddef>
#include <cstdint>

// Problem constants
constexpr int Bz = 8, CIN = 256, Hh = 96, Ww = 96;
constexpr int EMB1 = 256, EMB2 = 128, NCLS = 80;
constexpr int HP = 98; // padded spatial
constexpr size_t PIX = (size_t)Hh * Ww;                 // 9216
constexpr size_t XP_ELEMS = (size_t)Bz * HP * HP * CIN; // 19,668,992 bf16 elems

// Output layout (flat concat, fp32)
constexpr size_t O0 = 0;                       // cls_score      (B,80,96,96)
constexpr size_t O1 = (size_t)Bz * NCLS * PIX; // cls_score_neg
constexpr size_t O2 = 2 * O1;                  // distances
constexpr size_t O3 = 3 * O1;                  // distances_neg  (B,80,3,96,96)
constexpr size_t O4 = 6 * O1;                  // probs_ori

typedef short bf16x8 __attribute__((ext_vector_type(8)));
typedef float f32x4 __attribute__((ext_vector_type(4)));

__device__ inline unsigned short f2bf(float f) {
  union { float f; unsigned int u; } v; v.f = f;
  unsigned int r = v.u + 0x7fffu + ((v.u >> 16) & 1u);
  return (unsigned short)(r >> 16);
}

// async global->LDS, 16B per lane; LDS dest = wave-uniform base + lane*16
#define GLD16(gp, lp)                                              \
  __builtin_amdgcn_global_load_lds(                                \
      (__attribute__((address_space(1))) void*)((void*)(gp)),      \
      (__attribute__((address_space(3))) void*)(lp), 16, 0, 0)

// ---------------------------------------------------------------------------
// Prep: x (NCHW fp32) -> padded NHWC bf16, zero border
__global__ __launch_bounds__(256) void pad_x_kernel(const float* __restrict__ x,
                                                    unsigned short* __restrict__ xp) {
  const int p = blockIdx.x;       // 0..98*98-1
  const int b = blockIdx.y;
  const int ic = threadIdx.x;     // 0..255
  const int y = p / HP, xx = p % HP;
  float v = 0.f;
  if (y >= 1 && y <= Hh && xx >= 1 && xx <= Ww)
    v = x[(((size_t)b * CIN + ic) * Hh + (y - 1)) * Ww + (xx - 1)];
  xp[((size_t)b * (HP * HP) + p) * CIN + ic] = f2bf(v);
}

// Prep: weights -> bf16 [tap][oc][ic]; BN fold (fp32 scale/offset)
__global__ __launch_bounds__(256) void prep_w_kernel(
    const float* __restrict__ w1, const float* __restrict__ w2,
    const float* __restrict__ c1b, const float* __restrict__ g,
    const float* __restrict__ be, const float* __restrict__ mu,
    const float* __restrict__ var, unsigned short* __restrict__ wt1,
    unsigned short* __restrict__ wt2, float* __restrict__ bns,
    float* __restrict__ bno) {
  const int idx = blockIdx.x * 256 + threadIdx.x;
  if (idx < 9 * 256 * 256) {  // wt1[tap][oc][ic]
    const int ic = idx & 255, oc = (idx >> 8) & 255, tap = idx >> 16;
    wt1[idx] = f2bf(w1[((size_t)(oc * 256 + ic)) * 9 + tap]);
  }
  if (idx < 9 * 128 * 256) {  // wt2[tap][oc][ic]
    const int ic = idx & 255, oc = (idx >> 8) & 127, tap = idx >> 15;
    wt2[idx] = f2bf(w2[((size_t)(oc * 256 + ic)) * 9 + tap]);
  }
  if (idx < 256) {
    const float s = g[idx] * rsqrtf(var[idx] + 1e-5f);
    bns[idx] = s;
    bno[idx] = (c1b[idx] - mu[idx]) * s + be[idx];
  }
}

// reps = l2norm(rep_w[:,0] + rep_b) per class (80 x 128); fp32 rpv + bf16 Rb
__global__ __launch_bounds__(128) void rep_norm_kernel(const float* __restrict__ rw,
                                                       const float* __restrict__ rb,
                                                       float* __restrict__ r,
                                                       unsigned short* __restrict__ Rb) {
  __shared__ float red[2];
  const int c = blockIdx.x, t = threadIdx.x;
  const float v = rw[c * 128 + t] + rb[c * 128 + t];
  float s = v * v;
  for (int msk = 1; msk < 64; msk <<= 1) s += __shfl_xor(s, msk, 64);
  if ((t & 63) == 0) red[t >> 6] = s;
  __syncthreads();
  const float ss = red[0] + red[1];
  const float rn = 1.f / fmaxf(sqrtf(ss), 1e-12f);
  r[c * 128 + t] = v * rn;
  Rb[(size_t)(c * 4) * 128 + t] = f2bf(v * rn);  // rep slot v=0 (positive)
}

// reps_neg: per (class, neg) 3-layer MLP on r, then l2norm -> bf16 Rb slot
__global__ __launch_bounds__(128) void mlp_neg_kernel(const float* __restrict__ r,
                                                      const float* __restrict__ W,
                                                      const float* __restrict__ bb,
                                                      unsigned short* __restrict__ Rb) {
  __shared__ float h0[128], h1[128];
  __shared__ float red[2];
  const int c = blockIdx.x, ng = blockIdx.y, t = threadIdx.x;
  h0[t] = r[c * 128 + t];
  __syncthreads();
  float s = 0.f;
  for (int lay = 0; lay < 3; ++lay) {
    const float* hin = (lay & 1) ? h1 : h0;
    float* hout = (lay & 1) ? h0 : h1;
    const float* wr = W + (((size_t)ng * 3 + lay) * 128 + t) * 128;
    s = bb[(ng * 3 + lay) * 128 + t];
    for (int e = 0; e < 128; ++e) s += wr[e] * hin[e];
    if (lay < 2) hout[t] = fmaxf(s, 0.f);
    __syncthreads();
  }
  float q = s * s;
  for (int msk = 1; msk < 64; msk <<= 1) q += __shfl_xor(q, msk, 64);
  if ((t & 63) == 0) red[t >> 6] = q;
  __syncthreads();
  const float ss = red[0] + red[1];
  const float rn = 1.f / fmaxf(sqrtf(ss), 1e-12f);
  Rb[((size_t)(c * 4) + 1 + ng) * 128 + t] = f2bf(s * rn);
}

// ---------------------------------------------------------------------------
// bf16 MFMA implicit-GEMM 3x3 conv, NHWC (padded input HPxHP, IC=256).
// Block tile: 128 px (8 rows x 16 cols) x 128 oc. BK=32. 4 waves, each 64x64
// via 4x4 grid of mfma_f32_16x16x32_bf16. global_load_lds width-16 staging.
// BN=true: out bf16 padded NHWC (B,98,98,256) at (y+1,x+1), v=acc*e0+e1
// BN=false: out bf16 NHWC (B,96,96,128), v=l2norm_c(acc+e0) (fused l2norm)
template <int OC, bool BN>
__global__ __launch_bounds__(256) void conv3x3_mfma(
    const unsigned short* __restrict__ in, const unsigned short* __restrict__ wt,
    const float* __restrict__ e0, const float* __restrict__ e1,
    unsigned short* __restrict__ out16) {
  __shared__ unsigned short smA[128 * 32];  // [px][k] 64B rows
  __shared__ unsigned short smB[128 * 32];  // [oc][k]
  __shared__ float nrm[128][2];             // fused l2norm partials (BN=false)
  const int tile = blockIdx.x;              // 0..71
  const int oc0 = blockIdx.y * 128;
  const int b = blockIdx.z;
  const int ty = (tile / 6) * 8, tx = (tile % 6) * 16;
  const int t = threadIdx.x;
  const int lane = t & 63, w = t >> 6;
  const int wm = w & 1, wn = w >> 1;
  const int quad = lane >> 4, col = lane & 15;
  const int chl = (lane & 3) * 8;           // staging channel sub-offset

  int rowA[2], colA[2], ocB[2];
#pragma unroll
  for (int i = 0; i < 2; ++i) {
    const int px = (w * 2 + i) * 16 + (lane >> 2);
    rowA[i] = ty + (px >> 4);
    colA[i] = tx + (px & 15);
    ocB[i] = oc0 + (w * 2 + i) * 16 + (lane >> 2);
  }

  f32x4 acc[4][4];
#pragma unroll
  for (int mt = 0; mt < 4; ++mt)
#pragma unroll
    for (int nt = 0; nt < 4; ++nt) acc[mt][nt] = {0.f, 0.f, 0.f, 0.f};

  for (int tap = 0; tap < 9; ++tap) {
    const int ky = tap / 3, kx = tap % 3;
    const unsigned short* aB[2];
    const unsigned short* bB[2];
#pragma unroll
    for (int i = 0; i < 2; ++i) {
      aB[i] = in + (((size_t)b * HP + rowA[i] + ky) * HP + colA[i] + kx) * 256 + chl;
      bB[i] = wt + ((size_t)(tap * OC + ocB[i])) * 256 + chl;
    }
    for (int ch0 = 0; ch0 < 256; ch0 += 32) {
      __syncthreads();
      GLD16(aB[0] + ch0, (char*)smA + (w * 2 + 0) * 1024);
      GLD16(aB[1] + ch0, (char*)smA + (w * 2 + 1) * 1024);
      GLD16(bB[0] + ch0, (char*)smB + (w * 2 + 0) * 1024);
      GLD16(bB[1] + ch0, (char*)smB + (w * 2 + 1) * 1024);
      __syncthreads();
      bf16x8 af[4], bf[4];
#pragma unroll
      for (int mt = 0; mt < 4; ++mt)
        af[mt] = *(const bf16x8*)((const char*)smA +
                                  (wm * 64 + mt * 16 + col) * 64 + quad * 16);
#pragma unroll
      for (int nt = 0; nt < 4; ++nt)
        bf[nt] = *(const bf16x8*)((const char*)smB +
                                  (wn * 64 + nt * 16 + col) * 64 + quad * 16);
#pragma unroll
      for (int mt = 0; mt < 4; ++mt)
#pragma unroll
        for (int nt = 0; nt < 4; ++nt)
          acc[mt][nt] = __builtin_amdgcn_mfma_f32_16x16x32_bf16(
              af[mt], bf[nt], acc[mt][nt], 0, 0, 0);
    }
  }

  // epilogue
  float sc[4], of[4];
#pragma unroll
  for (int nt = 0; nt < 4; ++nt) {
    const int oc = oc0 + wn * 64 + nt * 16 + col;
    sc[nt] = e0[oc];
    of[nt] = BN ? e1[oc] : 0.f;
  }
  if (BN) {
#pragma unroll
    for (int mt = 0; mt < 4; ++mt)
#pragma unroll
      for (int r = 0; r < 4; ++r) {
        const int px = wm * 64 + mt * 16 + quad * 4 + r;
        const int y = ty + (px >> 4), x = tx + (px & 15);
        unsigned short* rowp =
            out16 + (((size_t)b * HP + y + 1) * HP + x + 1) * 256 + oc0 + wn * 64 + col;
#pragma unroll
        for (int nt = 0; nt < 4; ++nt)
          rowp[nt * 16] = f2bf(acc[mt][nt][r] * sc[nt] + of[nt]);
      }
  } else {
    // fused channel l2norm: this block owns ALL 128 output channels per px
    float part[4][4];
#pragma unroll
    for (int mt = 0; mt < 4; ++mt)
#pragma unroll
      for (int r = 0; r < 4; ++r) {
        float s = 0.f;
#pragma unroll
        for (int nt = 0; nt < 4; ++nt) {
          const float v = acc[mt][nt][r] + sc[nt];
          s += v * v;
        }
        part[mt][r] = s;
      }
#pragma unroll
    for (int msk = 1; msk < 16; msk <<= 1)
#pragma unroll
      for (int mt = 0; mt < 4; ++mt)
#pragma unroll
        for (int r = 0; r < 4; ++r)
          part[mt][r] += __shfl_xor(part[mt][r], msk, 64);
    if (col == 0) {
#pragma unroll
      for (int mt = 0; mt < 4; ++mt)
#pragma unroll
        for (int r = 0; r < 4; ++r)
          nrm[wm * 64 + mt * 16 + quad * 4 + r][wn] = part[mt][r];
    }
    __syncthreads();
#pragma unroll
    for (int mt = 0; mt < 4; ++mt)
#pragma unroll
      for (int r = 0; r < 4; ++r) {
        const int px = wm * 64 + mt * 16 + quad * 4 + r;
        const int y = ty + (px >> 4), x = tx + (px & 15);
        const float nn = nrm[px][0] + nrm[px][1];
        const float rn = 1.f / fmaxf(sqrtf(nn), 1e-12f);
        unsigned short* rowp =
            out16 + (((size_t)b * Hh + y) * Ww + x) * 128 + wn * 64 + col;
#pragma unroll
        for (int nt = 0; nt < 4; ++nt)
          rowp[nt * 16] = f2bf((acc[mt][nt][r] + sc[nt]) * rn);
      }
  }
}

// ---------------------------------------------------------------------------
// 4x4 transpose across lanes differing in bits 0..1 (regs r0..r3)
__device__ inline void xpose4(float& r0, float& r1, float& r2, float& r3,
                              int lane) {
  const int b1 = (lane >> 1) & 1, b0 = lane & 1;
  float s0 = b1 ? r0 : r2;
  float s1 = b1 ? r1 : r3;
  s0 = __shfl_xor(s0, 2, 64);
  s1 = __shfl_xor(s1, 2, 64);
  if (b1) { r0 = s0; r1 = s1; } else { r2 = s0; r3 = s1; }
  float t0 = b0 ? r0 : r1;
  float t1 = b0 ? r2 : r3;
  t0 = __shfl_xor(t0, 1, 64);
  t1 = __shfl_xor(t1, 1, 64);
  if (b0) { r0 = t0; r2 = t1; } else { r1 = t0; r3 = t1; }
}

// Score: MFMA GEMM (64 px x 320 reps, K=128) + fused epilogue, no LDS.
// Rep order: n = cls*4 + {pos, neg0, neg1, neg2}. Wave w covers n in
// [w*80, w*80+80) as 5 n-tiles of 16.
__global__ __launch_bounds__(256) void score_mfma(
    const unsigned short* __restrict__ embb, const unsigned short* __restrict__ Rb,
    float* __restrict__ out) {
  const int px0 = blockIdx.x * 64;
  const int b = blockIdx.y;
  const int t = threadIdx.x;
  const int lane = t & 63, w = t >> 6;
  const int quad = lane >> 4, col = lane & 15;
  const int n0 = w * 80;
  const unsigned short* Abase = embb + ((size_t)b * PIX + px0) * 128;

  f32x4 acc[4][5];
#pragma unroll
  for (int mt = 0; mt < 4; ++mt)
#pragma unroll
    for (int nt = 0; nt < 5; ++nt) acc[mt][nt] = {0.f, 0.f, 0.f, 0.f};

#pragma unroll
  for (int ks = 0; ks < 4; ++ks) {
    bf16x8 bf[5], af[4];
#pragma unroll
    for (int nt = 0; nt < 5; ++nt)
      bf[nt] = *(const bf16x8*)(Rb + (size_t)(n0 + nt * 16 + col) * 128 +
                                ks * 32 + quad * 8);
#pragma unroll
    for (int mt = 0; mt < 4; ++mt)
      af[mt] = *(const bf16x8*)(Abase + (size_t)(mt * 16 + col) * 128 +
                                ks * 32 + quad * 8);
#pragma unroll
    for (int mt = 0; mt < 4; ++mt)
#pragma unroll
      for (int nt = 0; nt < 5; ++nt)
        acc[mt][nt] = __builtin_amdgcn_mfma_f32_16x16x32_bf16(
            af[mt], bf[nt], acc[mt][nt], 0, 0, 0);
  }

  const int j = lane & 3, kq = (lane >> 2) & 3;
#pragma unroll
  for (int mt = 0; mt < 4; ++mt) {
    const int px = px0 + mt * 16 + quad * 4 + j;
#pragma unroll
    for (int nt = 0; nt < 5; ++nt) {
      float v0 = acc[mt][nt][0], v1 = acc[mt][nt][1];
      float v2 = acc[mt][nt][2], v3 = acc[mt][nt][3];
      xpose4(v0, v1, v2, v3, lane);
      // lane now holds (dp, dn0, dn1, dn2) for (px, cls)
      const int gc = w * 20 + nt * 4 + kq;
      const float d2p = fmaxf(2.f - 2.f * v0, 0.f);
      const float dist = sqrtf(d2p);
      const float q0 = fmaxf(2.f - 2.f * v1, 0.f);
      const float q1 = fmaxf(2.f - 2.f * v2, 0.f);
      const float q2 = fmaxf(2.f - 2.f * v3, 0.f);
      const float dn0 = sqrtf(q0), dn1 = sqrtf(q1), dn2 = sqrtf(q2);
      const float pn = __expf(-2.f * fminf(q0, fminf(q1, q2)));
      const float pori = __expf(-2.f * d2p);
      const float minn = fminf(dn0, fminf(dn1, dn2));
      const float shifted = dist + 0.3f * fmaxf(2.0f - minn, 0.f);
      const float p = __expf(-2.f * shifted * shifted);
      const float clsv = __logf(fmaxf(p, 1e-5f) / fmaxf(1.f - p, 1e-5f));
      const size_t bc = ((size_t)b * NCLS + gc) * PIX + px;
      out[O0 + bc] = clsv;
      out[O1 + bc] = pn;
      out[O2 + bc] = dist;
      out[O4 + bc] = pori;
      const size_t b3 = (((size_t)b * NCLS + gc) * 3) * PIX + px;
      out[O3 + b3] = dn0;
      out[O3 + b3 + PIX] = dn1;
      out[O3 + b3 + 2 * PIX] = dn2;
    }
  }
}

// ---------------------------------------------------------------------------
extern "C" void kernel_launch(void* const* d_in, const int* in_sizes, int n_in,
                              void* d_out, int out_size, void* d_ws,
                              size_t ws_size, hipStream_t stream) {
  const float* x = (const float*)d_in[0];
  const float* w1 = (const float*)d_in[1];
  const float* c1b = (const float*)d_in[2];
  const float* g = (const float*)d_in[3];
  const float* be = (const float*)d_in[4];
  const float* mu = (const float*)d_in[5];
  const float* var = (const float*)d_in[6];
  const float* w2 = (const float*)d_in[7];
  const float* c2b = (const float*)d_in[8];
  const float* rw = (const float*)d_in[9];
  const float* rb = (const float*)d_in[10];
  const float* nw = (const float*)d_in[11];
  const float* nb = (const float*)d_in[12];
  float* out = (float*)d_out;

  unsigned short* xp = (unsigned short*)d_ws;   // bf16 padded NHWC input
  unsigned short* hp = xp + XP_ELEMS;           // bf16 padded NHWC hidden
  unsigned short* wt1 = hp + XP_ELEMS;          // 589,824 bf16
  unsigned short* wt2 = wt1 + 589824;           // 294,912 bf16
  float* bns = (float*)(wt2 + 294912);
  float* bno = bns + 256;
  float* rpv = bno + 256;                       // 10,240 fp32
  unsigned short* Rb = (unsigned short*)(rpv + 10240);  // 40,960 bf16
  unsigned short* embb = xp;                    // alias: xp dead after conv1

  hipMemsetAsync(hp, 0, XP_ELEMS * sizeof(unsigned short), stream);
  pad_x_kernel<<<dim3(HP * HP, Bz), 256, 0, stream>>>(x, xp);
  prep_w_kernel<<<2304, 256, 0, stream>>>(w1, w2, c1b, g, be, mu, var, wt1, wt2,
                                          bns, bno);
  rep_norm_kernel<<<NCLS, 128, 0, stream>>>(rw, rb, rpv, Rb);
  mlp_neg_kernel<<<dim3(NCLS, 3), 128, 0, stream>>>(rpv, nw, nb, Rb);
  conv3x3_mfma<256, true><<<dim3(72, 2, Bz), 256, 0, stream>>>(xp, wt1, bns,
                                                               bno, hp);
  conv3x3_mfma<128, false><<<dim3(72, 1, Bz), 256, 0, stream>>>(hp, wt2, c2b,
                                                                nullptr, embb);
  score_mfma<<<dim3(144, Bz), 256, 0, stream>>>(embb, Rb, out);
}